// Round 8
// baseline (636.994 us; speedup 1.0000x reference)
//
#include <hip/hip_runtime.h>
#include <hip/hip_bf16.h>
#include <hip/hip_fp8.h>

// x: (64,3,384,384) f32; conv_w: (768,3,16,16) f32; conv_b: (768,) f32; latent: (1,1024,768) f32
// patches 24x24=576/img, M=36864, K=768, L=1024. pn padded to 640 rows/batch (5x128 tiles).
// All GEMMs in OCP fp8 e4m3 via MX-scaled MFMA 32x32x64 (K-tile 128, 6 iters).
// Scale encoding (e8m0): 127 -> 2^0, 123 -> 2^-4, 122 -> 2^-5.
// NO __launch_bounds__ on GEMM kernels: any waves-per-EU bound makes the unified-RF
// allocator split the budget 50/50 arch/AGPR (R5: 64 arch, R6/R7: 84 arch observed),
// starving the K-loop's ~115 arch regs -> 450+ MB scratch spill. Natural allocation
// (R4 precedent: 192 arch + 64 agpr) is spill-free.
#define KDIM   768
#define NPATCH 576
#define NPAD   640
#define NBATCH 64
#define MROWS  36864
#define LROWS  1024

typedef __attribute__((ext_vector_type(16))) float float16v;
typedef __attribute__((ext_vector_type(8))) int int8v;
typedef __attribute__((ext_vector_type(4))) int int4v;
typedef __attribute__((ext_vector_type(4))) float float4v;
typedef unsigned char u8;

__device__ inline u8 f2fp8(float f) { __hip_fp8_e4m3 t(f); return (u8)t.__x; }

__device__ __forceinline__ void gload_lds16(const u8* g, u8* l) {
    __builtin_amdgcn_global_load_lds(
        (const __attribute__((address_space(1))) unsigned int*)g,
        (__attribute__((address_space(3))) unsigned int*)l, 16, 0, 0);
}

// ---------------- im2col + fp8 cast (scale 1), 16 contiguous floats per thread ------
__global__ __launch_bounds__(256) void im2col_cast_v(const float* __restrict__ x,
                                                     u8* __restrict__ A) {
    int t = blockIdx.x * 256 + threadIdx.x;        // 36864*48 threads
    int row = t / 48;
    int ci = t - row * 48;                         // c*16 + i
    int c = ci >> 4, i = ci & 15;
    int b = row / NPATCH;
    int p = row - b * NPATCH;
    int ph = p / 24, pw = p - ph * 24;
    const float* src = x + (((size_t)b * 3 + c) * 384 + ph * 16 + i) * 384 + pw * 16;
    float4v f[4];
#pragma unroll
    for (int q = 0; q < 4; q++) f[q] = *(const float4v*)(src + q * 4);
    unsigned int o[4];
#pragma unroll
    for (int q = 0; q < 4; q++) {
        o[q] = 0;
#pragma unroll
        for (int e = 0; e < 4; e++) o[q] |= ((unsigned int)f2fp8(f[q][e])) << (8 * e);
    }
    *(int4v*)(A + (size_t)row * KDIM + c * 256 + i * 16) = *(int4v*)o;
}

// ---------------- conv_w -> fp8(w*32), used with B-scale 2^-5 ------------------------
__global__ __launch_bounds__(256) void cast_w(const float* __restrict__ src,
                                              u8* __restrict__ dst) {
    int t = blockIdx.x * 256 + threadIdx.x;        // 36864 threads, 16 elems each
    const float* s = src + (size_t)t * 16;
    unsigned int o[4];
#pragma unroll
    for (int q = 0; q < 4; q++) {
        float4v f = *(const float4v*)(s + q * 4);
        o[q] = 0;
#pragma unroll
        for (int e = 0; e < 4; e++) o[q] |= ((unsigned int)f2fp8(f[e] * 32.0f)) << (8 * e);
    }
    *(int4v*)(dst + (size_t)t * 16) = *(int4v*)o;
}

// ---------------- latent: L2-normalize f32 -> fp8(ln*16), one wave per row -----------
__global__ __launch_bounds__(256) void normalize_latent(const float* __restrict__ src,
                                                        u8* __restrict__ dst) {
    int wave = threadIdx.x >> 6, lane = threadIdx.x & 63;
    int row = blockIdx.x * 4 + wave;               // 256 blocks
    const float4v* pr = (const float4v*)(src + (size_t)row * KDIM);
    float4v v[3];
    float ss = 0.f;
#pragma unroll
    for (int c = 0; c < 3; c++) {
        v[c] = pr[lane + 64 * c];
#pragma unroll
        for (int e = 0; e < 4; e++) ss += v[c][e] * v[c][e];
    }
#pragma unroll
    for (int off = 32; off; off >>= 1) ss += __shfl_xor(ss, off);
    float scale = 16.0f / fmaxf(sqrtf(ss), 1e-8f);
#pragma unroll
    for (int c = 0; c < 3; c++) {
        unsigned int o = 0;
#pragma unroll
        for (int e = 0; e < 4; e++) o |= ((unsigned int)f2fp8(v[c][e] * scale)) << (8 * e);
        *(unsigned int*)(dst + (size_t)row * KDIM + c * 256 + lane * 4) = o;
    }
}

// ---------------- inverse row norms from summed squares (padded index space) --------
__global__ __launch_bounds__(256) void inv_norm(const float* __restrict__ rssq,
                                                float* __restrict__ rn) {
    int t = blockIdx.x * 256 + threadIdx.x;        // 160 blocks -> 40960
    int p = t % NPAD;
    rn[t] = (p < NPATCH) ? (1.0f / fmaxf(sqrtf(rssq[t]), 1e-8f)) : 0.0f;
}

// ---------------- fp8 MX GEMM mainloop (C = A . B^T, both row-major K, fp8) ----------
// 256 threads, 4 waves 2x2, each wave 64x64 = 2x2 frags of 32x32x64 scaled MFMA.
// LDS tiles 128x128 fp8 (16 KB each) staged via global_load_lds width 16.
// 32B-granule swizzle: phys granule = (logical + row) & 3 -> single int8v derefs.
__device__ __forceinline__ void gemm_mainloop_fp8(const u8* __restrict__ Ab,
                                                  const u8* __restrict__ Bb,
                                                  u8* As, u8* Bs,
                                                  float16v acc[2][2], int sA, int sB) {
    int tid = threadIdx.x;
    int wave = tid >> 6, lane = tid & 63;
    int l31 = lane & 31, kh = lane >> 5;
    int wm = wave & 1, wn = wave >> 1;
    int lr = lane >> 3;                             // staging row 0..7
    int pg = (lane >> 1) & 3, h = lane & 1;
    int gofs = (((pg - lr) & 3) << 5) | (h << 4);   // global byte offset in row
    const u8* ga = Ab + (size_t)(wave * 32 + lr) * KDIM + gofs;
    const u8* gb = Bb + (size_t)(wave * 32 + lr) * KDIM + gofs;
    u8* lA = As + (wave * 32) * 128;                // wave-uniform LDS bases
    u8* lB = Bs + (wave * 32) * 128;
    const u8* ra0 = As + (wm * 64 + l31) * 128;     // per-lane read row bases
    const u8* ra1 = ra0 + 32 * 128;
    const u8* rb0 = Bs + (wn * 64 + l31) * 128;
    const u8* rb1 = rb0 + 32 * 128;
    for (int ks = 0; ks < KDIM; ks += 128) {
#pragma unroll
        for (int i = 0; i < 4; i++) {
            gload_lds16(ga + (size_t)(i * 8) * KDIM + ks, lA + i * 8 * 128);
            gload_lds16(gb + (size_t)(i * 8) * KDIM + ks, lB + i * 8 * 128);
        }
        __syncthreads();
#pragma unroll
        for (int kk = 0; kk < 2; kk++) {
            int ofs = (((kk << 1) + kh + l31) & 3) << 5;
            int8v a0 = *(const int8v*)(ra0 + ofs);
            int8v b0 = *(const int8v*)(rb0 + ofs);
            acc[0][0] = __builtin_amdgcn_mfma_scale_f32_32x32x64_f8f6f4(
                a0, b0, acc[0][0], 0, 0, 0, sA, 0, sB);
            int8v b1 = *(const int8v*)(rb1 + ofs);
            acc[0][1] = __builtin_amdgcn_mfma_scale_f32_32x32x64_f8f6f4(
                a0, b1, acc[0][1], 0, 0, 0, sA, 0, sB);
            int8v a1 = *(const int8v*)(ra1 + ofs);
            acc[1][0] = __builtin_amdgcn_mfma_scale_f32_32x32x64_f8f6f4(
                a1, b0, acc[1][0], 0, 0, 0, sA, 0, sB);
            acc[1][1] = __builtin_amdgcn_mfma_scale_f32_32x32x64_f8f6f4(
                a1, b1, acc[1][1], 0, 0, 0, sA, 0, sB);
        }
        __syncthreads();
    }
}

// C/D layout for 32x32 shapes: col = lane&31, row = (reg&3) + 8*(reg>>2) + 4*(lane>>5)
#define RLOC(r, kh) (((r) & 3) + 8 * ((r) >> 2) + 4 * (kh))

__device__ __forceinline__ float block_reduce_sum(float s, float* red) {
#pragma unroll
    for (int off = 32; off; off >>= 1) s += __shfl_down(s, off);
    int wave = threadIdx.x >> 6, lane = threadIdx.x & 63;
    if (lane == 0) red[wave] = s;
    __syncthreads();
    return red[0] + red[1] + red[2] + red[3];
}

// ---------------- conv GEMM: A(x,s=1) . Wm^T(w*32,s=2^-5) + bias -> pn fp8(v*16) -----
__global__ void gemm_conv(const u8* __restrict__ A,
                          const u8* __restrict__ Wm,
                          const float* __restrict__ bias,
                          u8* __restrict__ pn,
                          float* __restrict__ rssq) {
    __shared__ u8 As[128 * 128], Bs[128 * 128];
    int xcd = blockIdx.x & 7, q = blockIdx.x >> 3;   // 1728 blocks: 288 mb x 6 nb
    int mb = xcd * 36 + q / 6;                       // contiguous mb strip per XCD
    int nb = q % 6;
    int wave = threadIdx.x >> 6, lane = threadIdx.x & 63;
    int l31 = lane & 31, kh = lane >> 5;
    int wm = wave & 1, wn = wave >> 1;
    float16v acc[2][2] = {};
    gemm_mainloop_fp8(A + (size_t)mb * 128 * KDIM, Wm + (size_t)nb * 128 * KDIM,
                      As, Bs, acc, 0x7F7F7F7F, 0x7A7A7A7A);
    float bv[2];
#pragma unroll
    for (int co = 0; co < 2; co++) bv[co] = bias[nb * 128 + wn * 64 + co * 32 + l31];
#pragma unroll
    for (int ro = 0; ro < 2; ro++) {
#pragma unroll
        for (int r = 0; r < 16; r++) {
            int row = mb * 128 + wm * 64 + ro * 32 + RLOC(r, kh);
            int b = row / NPATCH;
            int prow = row + b * 64;               // padded row index
            float ssq = 0.f;
#pragma unroll
            for (int co = 0; co < 2; co++) {
                int col = nb * 128 + wn * 64 + co * 32 + l31;
                float v = acc[ro][co][r] + bv[co];
                ssq += v * v;
                pn[(size_t)prow * KDIM + col] = f2fp8(v * 16.0f);
            }
#pragma unroll
            for (int off = 1; off < 32; off <<= 1) ssq += __shfl_xor(ssq, off);
            if (l31 == 0) atomicAdd(&rssq[prow], ssq);
        }
    }
}

// ---------------- SIM GEMM: per batch 640x640 (valid 576), sum off-diag exp(2*cos) --
__global__ void gemm_sim(const u8* __restrict__ pn,
                         const float* __restrict__ rn,
                         float* __restrict__ far_sum) {
    __shared__ u8 As[128 * 128], Bs[128 * 128];
    __shared__ float red[4];
    int xcd = blockIdx.x & 7, q = blockIdx.x >> 3;   // 1600 blocks: 64 batches x 25
    int b = xcd * 8 + q / 25;                        // 8 batches per XCD
    int t = q % 25;
    int mt = t / 5, nt = t - mt * 5;
    int wave = threadIdx.x >> 6, lane = threadIdx.x & 63;
    int l31 = lane & 31, kh = lane >> 5;
    int wm = wave & 1, wn = wave >> 1;
    const u8* base = pn + (size_t)b * NPAD * KDIM;
    float16v acc[2][2] = {};
    gemm_mainloop_fp8(base + (size_t)mt * 128 * KDIM, base + (size_t)nt * 128 * KDIM,
                      As, Bs, acc, 0x7B7B7B7B, 0x7B7B7B7B);
    const float* rnb = rn + b * NPAD;
    float rcol[2];
#pragma unroll
    for (int co = 0; co < 2; co++) rcol[co] = rnb[nt * 128 + wn * 64 + co * 32 + l31];
    float s = 0.f;
#pragma unroll
    for (int ro = 0; ro < 2; ro++) {
#pragma unroll
        for (int r = 0; r < 16; r++) {
            int row = mt * 128 + wm * 64 + ro * 32 + RLOC(r, kh);
            if (row < NPATCH) {
                float rrow = rnb[row];
#pragma unroll
                for (int co = 0; co < 2; co++) {
                    int col = nt * 128 + wn * 64 + co * 32 + l31;
                    if (col < NPATCH && row != col)
                        s += __expf(2.0f * acc[ro][co][r] * rrow * rcol[co]);
                }
            }
        }
    }
    float tot = block_reduce_sum(s, red);
    if (threadIdx.x == 0) atomicAdd(&far_sum[b], tot);
}

// ---------------- close GEMM: pn . Lm^T (both *16, scales 2^-4), per-batch sums ------
__global__ void gemm_close(const u8* __restrict__ pn,
                           const u8* __restrict__ Lm,
                           const float* __restrict__ rn,
                           float* __restrict__ close_sum) {
    __shared__ u8 As[128 * 128], Bs[128 * 128];
    __shared__ float red[4];
    int xcd = blockIdx.x & 7, q = blockIdx.x >> 3;   // 2560 blocks: 320 mb x 8 nb
    int mb = xcd * 40 + (q >> 3);                    // contiguous mb strip per XCD
    int nb = q & 7;
    int wave = threadIdx.x >> 6, lane = threadIdx.x & 63;
    int l31 = lane & 31, kh = lane >> 5;
    int wm = wave & 1, wn = wave >> 1;
    float16v acc[2][2] = {};
    gemm_mainloop_fp8(pn + (size_t)mb * 128 * KDIM, Lm + (size_t)nb * 128 * KDIM,
                      As, Bs, acc, 0x7B7B7B7B, 0x7B7B7B7B);
    int batch = mb / 5;
    int ptile = (mb - batch * 5) * 128;              // row offset within batch
    float s = 0.f;
#pragma unroll
    for (int ro = 0; ro < 2; ro++) {
#pragma unroll
        for (int r = 0; r < 16; r++) {
            int p = ptile + wm * 64 + ro * 32 + RLOC(r, kh);
            if (p < NPATCH) {
                float rrow = rn[batch * NPAD + p];
#pragma unroll
                for (int co = 0; co < 2; co++)
                    s += __expf(2.0f * acc[ro][co][r] * rrow);
            }
        }
    }
    float tot = block_reduce_sum(s, red);
    if (threadIdx.x == 0) atomicAdd(&close_sum[batch], tot);
}

// ---------------- final loss ----------------
__global__ void loss_kernel(const float* __restrict__ far_sum,
                            const float* __restrict__ close_sum,
                            float* __restrict__ out) {
    int t = threadIdx.x;  // 64
    float v = logf(far_sum[t]) - logf(close_sum[t]);
#pragma unroll
    for (int off = 32; off; off >>= 1) v += __shfl_xor(v, off);
    if (t == 0) out[0] = v * (1.0f / 64.0f);
}

extern "C" void kernel_launch(void* const* d_in, const int* in_sizes, int n_in,
                              void* d_out, int out_size, void* d_ws, size_t ws_size,
                              hipStream_t stream) {
    const float* x      = (const float*)d_in[0];
    const float* conv_w = (const float*)d_in[1];
    const float* conv_b = (const float*)d_in[2];
    const float* latent = (const float*)d_in[3];
    float* out = (float*)d_out;
    char* ws = (char*)d_ws;

    // workspace layout (bytes):
    // pn (40960x768 fp8, 640 rows/batch):  0          .. 31,457,280
    // A  (im2col 36864x768 fp8):           31,457,280 .. 59,768,832
    //   rn (40960 f32) overlays A (A dead after gemm_conv; rn written after)
    // Wm (768x768 fp8, *32):               59,768,832 .. 60,358,656
    // Lm (1024x768 fp8, *16):              60,358,656 .. 61,145,088
    // rssq (40960 f32) + sums (128 f32):   61,145,088 .. 61,309,440
    u8* pn = (u8*)ws;
    u8* A  = (u8*)(ws + 31457280);
    u8* Wm = (u8*)(ws + 59768832);
    u8* Lm = (u8*)(ws + 60358656);
    float* rssq = (float*)(ws + 61145088);
    float* sums = (float*)(ws + 61308928);
    float* rn   = (float*)(ws + 31457280);   // overlays A
    float* far_sum = sums;
    float* close_sum = sums + 64;

    hipMemsetAsync(rssq, 0, (40960 + 128) * sizeof(float), stream);  // rssq + sums
    im2col_cast_v<<<36864 * 48 / 256, 256, 0, stream>>>(x, A);
    cast_w<<<144, 256, 0, stream>>>(conv_w, Wm);
    normalize_latent<<<LROWS / 4, 256, 0, stream>>>(latent, Lm);

    gemm_conv<<<288 * 6, 256, 0, stream>>>(A, Wm, conv_b, pn, rssq);
    inv_norm<<<160, 256, 0, stream>>>(rssq, rn);

    gemm_sim<<<NBATCH * 25, 256, 0, stream>>>(pn, rn, far_sum);
    gemm_close<<<320 * 8, 256, 0, stream>>>(pn, Lm, rn, close_sum);

    loss_kernel<<<1, 64, 0, stream>>>(far_sum, close_sum, out);
}

// Round 9
// 368.366 us; speedup vs baseline: 1.7292x; 1.7292x over previous
//
#include <hip/hip_runtime.h>
#include <hip/hip_bf16.h>
#include <hip/hip_fp8.h>

// x: (64,3,384,384) f32; conv_w: (768,3,16,16) f32; conv_b: (768,) f32; latent: (1,1024,768) f32
// patches 24x24=576/img, M=36864, K=768, L=1024. pn padded to 640 rows/batch (5x128 tiles).
// All GEMMs in OCP fp8 e4m3 via MX-scaled MFMA 16x16x128 (K-tile 128, 6 iters).
// Scale encoding (e8m0): 127 -> 2^0, 123 -> 2^-4, 122 -> 2^-5.
//
// REGISTER ALLOCATION NOTES (R5-R8 post-mortems):
//  * The 32x32x64 MFMA path (float16v acc tuples) makes the unified-RF allocator
//    arch-starve the kernel (64-84 arch VGPRs) under ALL bounds settings -> 450-553 MB
//    scratch spill. The 16x16x128 path (this file, R4-validated) allocates naturally
//    (192 arch + AGPR acc, zero spill). Do not switch shapes; do not add min-waves bounds.
//  * Staging addresses are uniformized via readfirstlane so global_load_lds can use
//    SGPR-base + shared 32-bit voffset (saddr form) instead of 8 VGPR pairs.
#define KDIM   768
#define NPATCH 576
#define NPAD   640
#define NBATCH 64
#define MROWS  36864
#define LROWS  1024

typedef __attribute__((ext_vector_type(8))) int int8v;
typedef __attribute__((ext_vector_type(4))) int int4v;
typedef __attribute__((ext_vector_type(4))) float float4v;
typedef unsigned char u8;

__device__ inline u8 f2fp8(float f) { __hip_fp8_e4m3 t(f); return (u8)t.__x; }

__device__ __forceinline__ void gload_lds16(const u8* g, u8* l) {
    __builtin_amdgcn_global_load_lds(
        (const __attribute__((address_space(1))) unsigned int*)g,
        (__attribute__((address_space(3))) unsigned int*)l, 16, 0, 0);
}

// ---------------- im2col + fp8 cast (scale 1), 16 contiguous floats per thread ------
__global__ __launch_bounds__(256) void im2col_cast_v(const float* __restrict__ x,
                                                     u8* __restrict__ A) {
    int t = blockIdx.x * 256 + threadIdx.x;        // 36864*48 threads
    int row = t / 48;
    int ci = t - row * 48;                         // c*16 + i
    int c = ci >> 4, i = ci & 15;
    int b = row / NPATCH;
    int p = row - b * NPATCH;
    int ph = p / 24, pw = p - ph * 24;
    const float* src = x + (((size_t)b * 3 + c) * 384 + ph * 16 + i) * 384 + pw * 16;
    float4v f[4];
#pragma unroll
    for (int q = 0; q < 4; q++) f[q] = *(const float4v*)(src + q * 4);
    unsigned int o[4];
#pragma unroll
    for (int q = 0; q < 4; q++) {
        o[q] = 0;
#pragma unroll
        for (int e = 0; e < 4; e++) o[q] |= ((unsigned int)f2fp8(f[q][e])) << (8 * e);
    }
    *(int4v*)(A + (size_t)row * KDIM + c * 256 + i * 16) = *(int4v*)o;
}

// ---------------- conv_w -> fp8(w*32), used with B-scale 2^-5 ------------------------
__global__ __launch_bounds__(256) void cast_w(const float* __restrict__ src,
                                              u8* __restrict__ dst) {
    int t = blockIdx.x * 256 + threadIdx.x;        // 36864 threads, 16 elems each
    const float* s = src + (size_t)t * 16;
    unsigned int o[4];
#pragma unroll
    for (int q = 0; q < 4; q++) {
        float4v f = *(const float4v*)(s + q * 4);
        o[q] = 0;
#pragma unroll
        for (int e = 0; e < 4; e++) o[q] |= ((unsigned int)f2fp8(f[e] * 32.0f)) << (8 * e);
    }
    *(int4v*)(dst + (size_t)t * 16) = *(int4v*)o;
}

// ---------------- latent: L2-normalize f32 -> fp8(ln*16), one wave per row -----------
__global__ __launch_bounds__(256) void normalize_latent(const float* __restrict__ src,
                                                        u8* __restrict__ dst) {
    int wave = threadIdx.x >> 6, lane = threadIdx.x & 63;
    int row = blockIdx.x * 4 + wave;               // 256 blocks
    const float4v* pr = (const float4v*)(src + (size_t)row * KDIM);
    float4v v[3];
    float ss = 0.f;
#pragma unroll
    for (int c = 0; c < 3; c++) {
        v[c] = pr[lane + 64 * c];
#pragma unroll
        for (int e = 0; e < 4; e++) ss += v[c][e] * v[c][e];
    }
#pragma unroll
    for (int off = 32; off; off >>= 1) ss += __shfl_xor(ss, off);
    float scale = 16.0f / fmaxf(sqrtf(ss), 1e-8f);
#pragma unroll
    for (int c = 0; c < 3; c++) {
        unsigned int o = 0;
#pragma unroll
        for (int e = 0; e < 4; e++) o |= ((unsigned int)f2fp8(v[c][e] * scale)) << (8 * e);
        *(unsigned int*)(dst + (size_t)row * KDIM + c * 256 + lane * 4) = o;
    }
}

// ---------------- inverse row norms from summed squares (padded index space) --------
__global__ __launch_bounds__(256) void inv_norm(const float* __restrict__ rssq,
                                                float* __restrict__ rn) {
    int t = blockIdx.x * 256 + threadIdx.x;        // 160 blocks -> 40960
    int p = t % NPAD;
    rn[t] = (p < NPATCH) ? (1.0f / fmaxf(sqrtf(rssq[t]), 1e-8f)) : 0.0f;
}

// ---------------- fp8 MX GEMM mainloop (C = A . B^T, both row-major K, fp8) ----------
// 256 threads, 4 waves 2x2, each wave 64x64 = 4x4 frags of 16x16x128 scaled MFMA.
// LDS tiles 128x128 fp8 (16 KB each) staged via global_load_lds width 16.
// 32B-granule XOR swizzle (R4-validated): phys granule = (global granule + row) & 3,
// with the two 16B halves of each granule kept in order.
__device__ __forceinline__ void gemm_mainloop_fp8(const u8* __restrict__ Ab,
                                                  const u8* __restrict__ Bb,
                                                  u8* As, u8* Bs,
                                                  float4v acc[4][4], int sA, int sB) {
    int tid = threadIdx.x;
    int lane = tid & 63;
    int wu = __builtin_amdgcn_readfirstlane(tid >> 6);   // wave id in SGPR
    int quad = lane >> 4, l15 = lane & 15;
    int wm = wu & 1, wn = wu >> 1;
    int lr = lane >> 3, ls = lane & 7;             // staging: 8 lanes x 16B per row
    int gs = ((((ls >> 1) - lr) & 3) << 1) | (ls & 1);   // swizzled global 16B seg
    int gvoff = lr * KDIM + gs * 16;               // per-lane byte offset (1 VGPR)
    const u8* gAu = Ab + (size_t)(wu * 32) * KDIM; // uniform bases (SGPR pairs)
    const u8* gBu = Bb + (size_t)(wu * 32) * KDIM;
    u8* lA = As + (wu * 32) * 128;                 // wave-uniform LDS bases
    u8* lB = Bs + (wu * 32) * 128;
    const u8* ra0 = As + (wm * 64 + l15) * 128;    // per-lane read row bases
    const u8* rb0 = Bs + (wn * 64 + l15) * 128;
    int lg = ((quad + (l15 & 3)) & 3) * 32;        // swizzled 32B granule for reads
    for (int ks = 0; ks < KDIM; ks += 128) {
#pragma unroll
        for (int i = 0; i < 4; i++) {
            gload_lds16(gAu + (ks + i * 8 * KDIM) + gvoff, lA + i * 1024);
            gload_lds16(gBu + (ks + i * 8 * KDIM) + gvoff, lB + i * 1024);
        }
        __syncthreads();
        int8v a[4], b[4];
#pragma unroll
        for (int i = 0; i < 4; i++)
            a[i] = *(const int8v*)(ra0 + i * 16 * 128 + lg);
#pragma unroll
        for (int j = 0; j < 4; j++)
            b[j] = *(const int8v*)(rb0 + j * 16 * 128 + lg);
#pragma unroll
        for (int i = 0; i < 4; i++)
#pragma unroll
            for (int j = 0; j < 4; j++)
                acc[i][j] = __builtin_amdgcn_mfma_scale_f32_16x16x128_f8f6f4(
                    a[i], b[j], acc[i][j], 0, 0, 0, sA, 0, sB);
        __syncthreads();
    }
}

__device__ __forceinline__ float block_reduce_sum(float s, float* red) {
#pragma unroll
    for (int off = 32; off; off >>= 1) s += __shfl_down(s, off);
    int wave = threadIdx.x >> 6, lane = threadIdx.x & 63;
    if (lane == 0) red[wave] = s;
    __syncthreads();
    return red[0] + red[1] + red[2] + red[3];
}

// ---------------- conv GEMM: A(x,s=1) . Wm^T(w*32,s=2^-5) + bias -> pn fp8(v*16) -----
__global__ __launch_bounds__(256) void gemm_conv(const u8* __restrict__ A,
                                                 const u8* __restrict__ Wm,
                                                 const float* __restrict__ bias,
                                                 u8* __restrict__ pn,
                                                 float* __restrict__ rssq) {
    __shared__ u8 As[128 * 128], Bs[128 * 128];
    int xcd = blockIdx.x & 7, q = blockIdx.x >> 3;   // 1728 blocks: 288 mb x 6 nb
    int mb = xcd * 36 + q / 6;                       // contiguous mb strip per XCD
    int nb = q % 6;
    int wave = threadIdx.x >> 6, lane = threadIdx.x & 63;
    int quad = lane >> 4, l15 = lane & 15;
    int wm = wave & 1, wn = wave >> 1;
    float4v acc[4][4] = {};
    gemm_mainloop_fp8(A + (size_t)mb * 128 * KDIM, Wm + (size_t)nb * 128 * KDIM,
                      As, Bs, acc, 0x7F7F7F7F, 0x7A7A7A7A);
    float bv[4];
#pragma unroll
    for (int j = 0; j < 4; j++) bv[j] = bias[nb * 128 + wn * 64 + j * 16 + l15];
#pragma unroll
    for (int i = 0; i < 4; i++) {
#pragma unroll
        for (int r = 0; r < 4; r++) {
            int row = mb * 128 + wm * 64 + i * 16 + quad * 4 + r;
            int b = row / NPATCH;
            int prow = row + b * 64;               // padded row index
            float ssq = 0.f;
#pragma unroll
            for (int j = 0; j < 4; j++) {
                int col = nb * 128 + wn * 64 + j * 16 + l15;
                float v = acc[i][j][r] + bv[j];
                ssq += v * v;
                pn[(size_t)prow * KDIM + col] = f2fp8(v * 16.0f);
            }
#pragma unroll
            for (int off = 1; off < 16; off <<= 1) ssq += __shfl_xor(ssq, off);
            if (l15 == 0) atomicAdd(&rssq[prow], ssq);
        }
    }
}

// ---------------- SIM GEMM: per batch 640x640 (valid 576), sum off-diag exp(2*cos) --
__global__ __launch_bounds__(256) void gemm_sim(const u8* __restrict__ pn,
                                                const float* __restrict__ rn,
                                                float* __restrict__ far_sum) {
    __shared__ u8 As[128 * 128], Bs[128 * 128];
    __shared__ float red[4];
    int xcd = blockIdx.x & 7, q = blockIdx.x >> 3;   // 1600 blocks: 64 batches x 25
    int b = xcd * 8 + q / 25;                        // 8 batches per XCD
    int t = q % 25;
    int mt = t / 5, nt = t - mt * 5;
    int wave = threadIdx.x >> 6, lane = threadIdx.x & 63;
    int quad = lane >> 4, l15 = lane & 15;
    int wm = wave & 1, wn = wave >> 1;
    const u8* base = pn + (size_t)b * NPAD * KDIM;
    float4v acc[4][4] = {};
    gemm_mainloop_fp8(base + (size_t)mt * 128 * KDIM, base + (size_t)nt * 128 * KDIM,
                      As, Bs, acc, 0x7B7B7B7B, 0x7B7B7B7B);
    const float* rnb = rn + b * NPAD;
    float rcol[4];
#pragma unroll
    for (int j = 0; j < 4; j++) rcol[j] = rnb[nt * 128 + wn * 64 + j * 16 + l15];
    float s = 0.f;
#pragma unroll
    for (int i = 0; i < 4; i++) {
#pragma unroll
        for (int r = 0; r < 4; r++) {
            int row = mt * 128 + wm * 64 + i * 16 + quad * 4 + r;
            if (row < NPATCH) {
                float rrow = rnb[row];
#pragma unroll
                for (int j = 0; j < 4; j++) {
                    int col = nt * 128 + wn * 64 + j * 16 + l15;
                    if (col < NPATCH && row != col)
                        s += __expf(2.0f * acc[i][j][r] * rrow * rcol[j]);
                }
            }
        }
    }
    float tot = block_reduce_sum(s, red);
    if (threadIdx.x == 0) atomicAdd(&far_sum[b], tot);
}

// ---------------- close GEMM: pn . Lm^T (both *16, scales 2^-4), per-batch sums ------
__global__ __launch_bounds__(256) void gemm_close(const u8* __restrict__ pn,
                                                  const u8* __restrict__ Lm,
                                                  const float* __restrict__ rn,
                                                  float* __restrict__ close_sum) {
    __shared__ u8 As[128 * 128], Bs[128 * 128];
    __shared__ float red[4];
    int xcd = blockIdx.x & 7, q = blockIdx.x >> 3;   // 2560 blocks: 320 mb x 8 nb
    int mb = xcd * 40 + (q >> 3);                    // contiguous mb strip per XCD
    int nb = q & 7;
    int wave = threadIdx.x >> 6, lane = threadIdx.x & 63;
    int quad = lane >> 4, l15 = lane & 15;
    int wm = wave & 1, wn = wave >> 1;
    float4v acc[4][4] = {};
    gemm_mainloop_fp8(pn + (size_t)mb * 128 * KDIM, Lm + (size_t)nb * 128 * KDIM,
                      As, Bs, acc, 0x7B7B7B7B, 0x7B7B7B7B);
    int batch = mb / 5;
    int ptile = (mb - batch * 5) * 128;              // row offset within batch
    float s = 0.f;
#pragma unroll
    for (int i = 0; i < 4; i++) {
#pragma unroll
        for (int r = 0; r < 4; r++) {
            int p = ptile + wm * 64 + i * 16 + quad * 4 + r;
            if (p < NPATCH) {
                float rrow = rn[batch * NPAD + p];
#pragma unroll
                for (int j = 0; j < 4; j++) s += __expf(2.0f * acc[i][j][r] * rrow);
            }
        }
    }
    float tot = block_reduce_sum(s, red);
    if (threadIdx.x == 0) atomicAdd(&close_sum[batch], tot);
}

// ---------------- final loss ----------------
__global__ void loss_kernel(const float* __restrict__ far_sum,
                            const float* __restrict__ close_sum,
                            float* __restrict__ out) {
    int t = threadIdx.x;  // 64
    float v = logf(far_sum[t]) - logf(close_sum[t]);
#pragma unroll
    for (int off = 32; off; off >>= 1) v += __shfl_xor(v, off);
    if (t == 0) out[0] = v * (1.0f / 64.0f);
}

extern "C" void kernel_launch(void* const* d_in, const int* in_sizes, int n_in,
                              void* d_out, int out_size, void* d_ws, size_t ws_size,
                              hipStream_t stream) {
    const float* x      = (const float*)d_in[0];
    const float* conv_w = (const float*)d_in[1];
    const float* conv_b = (const float*)d_in[2];
    const float* latent = (const float*)d_in[3];
    float* out = (float*)d_out;
    char* ws = (char*)d_ws;

    // workspace layout (bytes):
    // pn (40960x768 fp8, 640 rows/batch):  0          .. 31,457,280
    // A  (im2col 36864x768 fp8):           31,457,280 .. 59,768,832
    //   rn (40960 f32) overlays A (A dead after gemm_conv; rn written after)
    // Wm (768x768 fp8, *32):               59,768,832 .. 60,358,656
    // Lm (1024x768 fp8, *16):              60,358,656 .. 61,145,088
    // rssq (40960 f32) + sums (128 f32):   61,145,088 .. 61,309,440
    u8* pn = (u8*)ws;
    u8* A  = (u8*)(ws + 31457280);
    u8* Wm = (u8*)(ws + 59768832);
    u8* Lm = (u8*)(ws + 60358656);
    float* rssq = (float*)(ws + 61145088);
    float* sums = (float*)(ws + 61308928);
    float* rn   = (float*)(ws + 31457280);   // overlays A
    float* far_sum = sums;
    float* close_sum = sums + 64;

    hipMemsetAsync(rssq, 0, (40960 + 128) * sizeof(float), stream);  // rssq + sums
    im2col_cast_v<<<36864 * 48 / 256, 256, 0, stream>>>(x, A);
    cast_w<<<144, 256, 0, stream>>>(conv_w, Wm);
    normalize_latent<<<LROWS / 4, 256, 0, stream>>>(latent, Lm);

    gemm_conv<<<288 * 6, 256, 0, stream>>>(A, Wm, conv_b, pn, rssq);
    inv_norm<<<160, 256, 0, stream>>>(rssq, rn);

    gemm_sim<<<NBATCH * 25, 256, 0, stream>>>(pn, rn, far_sum);
    gemm_close<<<320 * 8, 256, 0, stream>>>(pn, Lm, rn, close_sum);

    loss_kernel<<<1, 64, 0, stream>>>(far_sum, close_sum, out);
}